// Round 10
// baseline (344.616 us; speedup 1.0000x reference)
//
#include <hip/hip_runtime.h>

typedef __bf16 bf16;
typedef __bf16 bf16x2 __attribute__((ext_vector_type(2)));
typedef __bf16 bf16x4 __attribute__((ext_vector_type(4)));
typedef __bf16 bf16x8 __attribute__((ext_vector_type(8)));
typedef float f32x4 __attribute__((ext_vector_type(4)));

typedef __attribute__((address_space(1))) const unsigned int gq_t;
typedef __attribute__((address_space(3))) unsigned int lq_t;

// ---------------------------------------------------------------------------
// fp32 -> bf16 converter, 8 elems/thread.
// ---------------------------------------------------------------------------
__global__ __launch_bounds__(256) void cvt_bf16(const float* __restrict__ in,
                                                bf16* __restrict__ out,
                                                int n8) {
  int i = blockIdx.x * 256 + threadIdx.x;
  if (i >= n8) return;
  f32x4 a = ((const f32x4*)in)[2 * i];
  f32x4 b = ((const f32x4*)in)[2 * i + 1];
  bf16x8 o;
#pragma unroll
  for (int j = 0; j < 4; ++j) {
    o[j] = (bf16)a[j];
    o[4 + j] = (bf16)b[j];
  }
  ((bf16x8*)out)[i] = o;
}

// ---------------------------------------------------------------------------
// bf16 GEMM, glds width-16 staging — ROUND-6 PROVEN SINGLE-BUFFER FORM
// (ran on HW at 328 us total). The 2-phase dbuf variant is parked: it
// coincided with 4/4 container failures (rounds 8-9) and has never executed;
// this round discriminates infra vs kernel by reverting to the proven base.
// ---------------------------------------------------------------------------
template <typename TC, bool ADD_BIAS>
__global__ __launch_bounds__(256) void gemm_glds(const bf16* __restrict__ A,
                                                 const bf16* __restrict__ B,
                                                 const float* __restrict__ bias,
                                                 TC* __restrict__ C,
                                                 int M, int N, int K, int lda) {
  __shared__ __align__(16) bf16 As[128 * 64];
  __shared__ __align__(16) bf16 Bs[128 * 64];
  const int tid = threadIdx.x;
  const int lane = tid & 63;
  const int wid = tid >> 6;
  const int wr = wid >> 1, wc = wid & 1;
  const int m0 = blockIdx.y * 128;
  const int n0 = blockIdx.x * 128;
  const int l16 = lane & 15;
  const int lhi = lane >> 4;
  const int lr = lane >> 3;
  const int lc = (lane & 7) * 8;

  f32x4 acc[4][4] = {};

  for (int k0 = 0; k0 < K; k0 += 64) {
    __syncthreads();
#pragma unroll
    for (int i = 0; i < 4; ++i) {
      const int chunk = wid * 4 + i;
      const int row = chunk * 8 + lr;
      const bf16* ga = A + (size_t)(m0 + row) * lda + k0 + lc;
      const bf16* gb = B + (size_t)(n0 + row) * K + k0 + lc;
      __builtin_amdgcn_global_load_lds((gq_t*)ga, (lq_t*)&As[chunk * 512], 16,
                                       0, 0);
      __builtin_amdgcn_global_load_lds((gq_t*)gb, (lq_t*)&Bs[chunk * 512], 16,
                                       0, 0);
    }
    __syncthreads();
#pragma unroll
    for (int ks = 0; ks < 2; ++ks) {
      bf16x8 af[4], bfr[4];
#pragma unroll
      for (int i = 0; i < 4; ++i) {
        af[i] = *(const bf16x8*)(&As[(wr * 64 + i * 16 + l16) * 64 + ks * 32 +
                                     lhi * 8]);
        bfr[i] = *(const bf16x8*)(&Bs[(wc * 64 + i * 16 + l16) * 64 + ks * 32 +
                                      lhi * 8]);
      }
#pragma unroll
      for (int i = 0; i < 4; ++i)
#pragma unroll
        for (int j = 0; j < 4; ++j)
          acc[i][j] = __builtin_amdgcn_mfma_f32_16x16x32_bf16(af[i], bfr[j],
                                                              acc[i][j], 0, 0, 0);
    }
  }

#pragma unroll
  for (int i = 0; i < 4; ++i) {
    int row_base = m0 + wr * 64 + i * 16 + lhi * 4;
#pragma unroll
    for (int j = 0; j < 4; ++j) {
      int col = n0 + wc * 64 + j * 16 + l16;
      float bv = ADD_BIAS ? bias[col] : 0.0f;
#pragma unroll
      for (int r = 0; r < 4; ++r) {
        float val = acc[i][j][r] + bv;
        if constexpr (__is_same(TC, float))
          C[(size_t)(row_base + r) * N + col] = val;
        else
          C[(size_t)(row_base + r) * N + col] = (bf16)val;
      }
    }
  }
}

// ---------------------------------------------------------------------------
// GEMM (legacy reg-staged, fp32 B): low-workspace fallback only.
// ---------------------------------------------------------------------------
template <typename TA, typename TC, bool ADD_BIAS>
__global__ __launch_bounds__(256) void gemm_bt(const TA* __restrict__ A,
                                               const float* __restrict__ B,
                                               const float* __restrict__ bias,
                                               TC* __restrict__ C,
                                               int M, int N, int K,
                                               int lda, int row0) {
  __shared__ __align__(16) bf16 As[128][72];
  __shared__ __align__(16) bf16 Bs[128][72];
  const int tid = threadIdx.x;
  const int lane = tid & 63;
  const int wid = tid >> 6;
  const int wr = wid >> 1, wc = wid & 1;
  const int m0 = blockIdx.y * 128;
  const int n0 = blockIdx.x * 128;
  const int l16 = lane & 15;
  const int lhi = lane >> 4;

  f32x4 acc[4][4] = {};

  for (int k0 = 0; k0 < K; k0 += 64) {
    __syncthreads();
#pragma unroll
    for (int p = 0; p < 8; ++p) {
      int v = tid + p * 256;
      int row = v >> 4;
      int kc = (v & 15) * 4;
      size_t ai = (size_t)(row0 + m0 + row) * lda + k0 + kc;
      size_t bi = (size_t)(n0 + row) * K + k0 + kc;
      bf16x4 ab, bb;
      if constexpr (__is_same(TA, float)) {
        f32x4 a4 = *(const f32x4*)((const float*)A + ai);
#pragma unroll
        for (int j = 0; j < 4; ++j) ab[j] = (bf16)a4[j];
      } else {
        ab = *(const bf16x4*)((const bf16*)A + ai);
      }
      f32x4 b4 = *(const f32x4*)(B + bi);
#pragma unroll
      for (int j = 0; j < 4; ++j) bb[j] = (bf16)b4[j];
      *(bf16x4*)(&As[row][kc]) = ab;
      *(bf16x4*)(&Bs[row][kc]) = bb;
    }
    __syncthreads();
#pragma unroll
    for (int ks = 0; ks < 2; ++ks) {
      bf16x8 af[4], bfr[4];
#pragma unroll
      for (int i = 0; i < 4; ++i) {
        af[i] = *(const bf16x8*)(&As[wr * 64 + i * 16 + l16][ks * 32 + lhi * 8]);
        bfr[i] = *(const bf16x8*)(&Bs[wc * 64 + i * 16 + l16][ks * 32 + lhi * 8]);
      }
#pragma unroll
      for (int i = 0; i < 4; ++i)
#pragma unroll
        for (int j = 0; j < 4; ++j)
          acc[i][j] = __builtin_amdgcn_mfma_f32_16x16x32_bf16(af[i], bfr[j],
                                                              acc[i][j], 0, 0, 0);
    }
  }

#pragma unroll
  for (int i = 0; i < 4; ++i) {
    int row_base = m0 + wr * 64 + i * 16 + lhi * 4;
#pragma unroll
    for (int j = 0; j < 4; ++j) {
      int col = n0 + wc * 64 + j * 16 + l16;
      float bv = ADD_BIAS ? bias[col] : 0.0f;
#pragma unroll
      for (int r = 0; r < 4; ++r) {
        float val = acc[i][j][r] + bv;
        if constexpr (__is_same(TC, float))
          C[(size_t)(row_base + r) * N + col] = val;
        else
          C[(size_t)(row_base + r) * N + col] = (bf16)val;
      }
    }
  }
}

// ---------------------------------------------------------------------------
// MFMA flash attention v9: 64 q-rows per wave (four 16-row sub-tiles).
//  - Next rung of the twice-confirmed amortization ladder (r5: 345->184,
//    r7: 184->143 with 2 sub-tiles). Staging/prefetch per block now serves
//    4x compute; Vt read pairs feed 8 MFMAs; K-frags read once per sub-tile
//    PAIR (twice/tile total) to cap live sc at 32 f32 — avoids the r1 spill
//    cliff. Block count 1024 -> 512.
//  - All proven pieces kept: K+V LDS double-buffer + 1-tile reg prefetch,
//    XCD swizzle, shuffle-free softmax, defer-max, exp2-direct, setprio,
//    single barrier/tile.
// ---------------------------------------------------------------------------
__global__ __launch_bounds__(256) void attn_fwd(bf16* __restrict__ qkv) {
  constexpr int S = 2048, D3 = 3072;
  constexpr float SCL = 0.18033688011112042f;  // 0.125 * log2(e)
  constexpr float THR = 11.5f;                 // 8 * log2(e)
  __shared__ __align__(16) bf16 Kt[2][64][72];  // [buf][key][dim]
  __shared__ __align__(16) bf16 Vt[2][64][72];  // [buf][dim][key]
  __shared__ __align__(16) bf16 Pq[4][16][72];  // per-wave transpose buffer

  const int tid = threadIdx.x;
  const int lane = tid & 63;
  const int wid = tid >> 6;
  const int l16 = lane & 15, lhi = lane >> 4;

  // XCD-aware bijective swizzle (nwg % 8 == 0 in all launch paths).
  const int nwg = gridDim.x * gridDim.y;  // 512 (full) / 128 (fallback)
  const int bid = blockIdx.y * gridDim.x + blockIdx.x;
  const int swz = (bid & 7) * (nwg >> 3) + (bid >> 3);
  const int bh = swz >> 3;                // 8 q-tiles (256 rows) per bh
  const int b = bh >> 4, h = bh & 15;
  const int q0 = (swz & 7) * 256 + wid * 64;  // wave owns rows q0..q0+63

  bf16* base = qkv + (size_t)b * S * D3;
  bf16* qbase = base + h * 64;
  const bf16* kbase = base + 1024 + h * 64;
  const bf16* vbase = base + 2048 + h * 64;

  // Q fragments for all four sub-tiles (cached before in-place overwrite)
  bf16x8 qf[4][2];
#pragma unroll
  for (int s = 0; s < 4; ++s)
#pragma unroll
    for (int ks = 0; ks < 2; ++ks)
      qf[s][ks] = *(const bf16x8*)(qbase + (size_t)(q0 + s * 16 + l16) * D3 +
                                   ks * 32 + lhi * 8);

  float m_i[4] = {-1e30f, -1e30f, -1e30f, -1e30f};  // log2 domain
  float l_p[4] = {};                                // per-lane partials
  f32x4 o[4][4] = {};

  const int kp = tid & 31, oc = tid >> 5;

  // prologue: stage K(0), V(0) into buffer 0
  {
    bf16x8 k0 = *(const bf16x8*)(kbase + (size_t)(2 * kp) * D3 + oc * 8);
    bf16x8 k1 = *(const bf16x8*)(kbase + (size_t)(2 * kp + 1) * D3 + oc * 8);
    bf16x8 v0 = *(const bf16x8*)(vbase + (size_t)(2 * kp) * D3 + oc * 8);
    bf16x8 v1 = *(const bf16x8*)(vbase + (size_t)(2 * kp + 1) * D3 + oc * 8);
    *(bf16x8*)(&Kt[0][2 * kp][oc * 8]) = k0;
    *(bf16x8*)(&Kt[0][2 * kp + 1][oc * 8]) = k1;
#pragma unroll
    for (int j = 0; j < 8; ++j) {
      bf16x2 pr;
      pr[0] = v0[j];
      pr[1] = v1[j];
      *(bf16x2*)(&Vt[0][oc * 8 + j][2 * kp]) = pr;
    }
  }
  __syncthreads();

  for (int t = 0; t < S; t += 64) {
    const int cur = (t >> 6) & 1;
    const bool havenext = (t + 64 < S);

    // issue next tile's K+V global loads FIRST
    bf16x8 kn0, kn1, vn0, vn1;
    if (havenext) {
      const bf16* kb = kbase + (size_t)(t + 64) * D3;
      const bf16* vb = vbase + (size_t)(t + 64) * D3;
      kn0 = *(const bf16x8*)(kb + (size_t)(2 * kp) * D3 + oc * 8);
      kn1 = *(const bf16x8*)(kb + (size_t)(2 * kp + 1) * D3 + oc * 8);
      vn0 = *(const bf16x8*)(vb + (size_t)(2 * kp) * D3 + oc * 8);
      vn1 = *(const bf16x8*)(vb + (size_t)(2 * kp + 1) * D3 + oc * 8);
    }

    bf16x8 pf[4][2];  // P fragments for all 4 sub-tiles (static indexing)

    // two sub-tile PAIRS: K-frags read once per pair, caps sc live at 32 f32
#pragma unroll
    for (int p = 0; p < 2; ++p) {
      f32x4 sc[2][4] = {};
      __builtin_amdgcn_s_setprio(1);
#pragma unroll
      for (int ct = 0; ct < 4; ++ct) {
#pragma unroll
        for (int ks = 0; ks < 2; ++ks) {
          bf16x8 kf = *(const bf16x8*)(&Kt[cur][ct * 16 + l16][ks * 32 + lhi * 8]);
          sc[0][ct] = __builtin_amdgcn_mfma_f32_16x16x32_bf16(
              kf, qf[2 * p][ks], sc[0][ct], 0, 0, 0);
          sc[1][ct] = __builtin_amdgcn_mfma_f32_16x16x32_bf16(
              kf, qf[2 * p + 1][ks], sc[1][ct], 0, 0, 0);
        }
      }
      __builtin_amdgcn_s_setprio(0);

#pragma unroll
      for (int j = 0; j < 2; ++j) {
        const int s = 2 * p + j;
        float cm[4];
#pragma unroll
        for (int ct = 0; ct < 4; ++ct)
          cm[ct] = fmaxf(fmaxf(sc[j][ct][0], sc[j][ct][1]),
                         fmaxf(sc[j][ct][2], sc[j][ct][3]));
        float mxs = fmaxf(fmaxf(cm[0], cm[1]), fmaxf(cm[2], cm[3])) * SCL;
        if (!__all(mxs - m_i[s] <= THR)) {
          float mw = mxs;
          mw = fmaxf(mw, __shfl_xor(mw, 16));
          mw = fmaxf(mw, __shfl_xor(mw, 32));
          float nm = fmaxf(m_i[s], mw);
          float alpha = __builtin_amdgcn_exp2f(m_i[s] - nm);
          m_i[s] = nm;
          l_p[s] *= alpha;
#pragma unroll
          for (int dt = 0; dt < 4; ++dt)
#pragma unroll
            for (int r = 0; r < 4; ++r) o[s][dt][r] *= alpha;
        }
        float rs4[4];
#pragma unroll
        for (int ct = 0; ct < 4; ++ct) {
#pragma unroll
          for (int r = 0; r < 4; ++r) {
            float pv = __builtin_amdgcn_exp2f(
                __builtin_fmaf(sc[j][ct][r], SCL, -m_i[s]));
            sc[j][ct][r] = pv;
          }
          rs4[ct] = (sc[j][ct][0] + sc[j][ct][1]) + (sc[j][ct][2] + sc[j][ct][3]);
        }
        l_p[s] += (rs4[0] + rs4[1]) + (rs4[2] + rs4[3]);

        // P stage via wave-private Pq (same-wave DS in-order: WAR safe)
#pragma unroll
        for (int ct = 0; ct < 4; ++ct) {
          bf16x4 pk;
#pragma unroll
          for (int r = 0; r < 4; ++r) pk[r] = (bf16)sc[j][ct][r];
          *(bf16x4*)(&Pq[wid][l16][ct * 16 + lhi * 4]) = pk;
        }
        pf[s][0] = *(const bf16x8*)(&Pq[wid][l16][lhi * 8]);
        pf[s][1] = *(const bf16x8*)(&Pq[wid][l16][32 + lhi * 8]);
      }
    }

    // stage K(t+1), V(t+1) into the other buffer
    if (havenext) {
      *(bf16x8*)(&Kt[cur ^ 1][2 * kp][oc * 8]) = kn0;
      *(bf16x8*)(&Kt[cur ^ 1][2 * kp + 1][oc * 8]) = kn1;
#pragma unroll
      for (int j = 0; j < 8; ++j) {
        bf16x2 pr;
        pr[0] = vn0[j];
        pr[1] = vn1[j];
        *(bf16x2*)(&Vt[cur ^ 1][oc * 8 + j][2 * kp]) = pr;
      }
    }

    // PV: Vt read pair feeds 8 MFMAs (all 4 sub-tiles)
    __builtin_amdgcn_s_setprio(1);
#pragma unroll
    for (int dt = 0; dt < 4; ++dt) {
      bf16x8 vf0 = *(const bf16x8*)(&Vt[cur][dt * 16 + l16][lhi * 8]);
      bf16x8 vf1 = *(const bf16x8*)(&Vt[cur][dt * 16 + l16][32 + lhi * 8]);
#pragma unroll
      for (int s = 0; s < 4; ++s) {
        o[s][dt] = __builtin_amdgcn_mfma_f32_16x16x32_bf16(vf0, pf[s][0],
                                                           o[s][dt], 0, 0, 0);
        o[s][dt] = __builtin_amdgcn_mfma_f32_16x16x32_bf16(vf1, pf[s][1],
                                                           o[s][dt], 0, 0, 0);
      }
    }
    __builtin_amdgcn_s_setprio(0);

    // single barrier: retires this tile's LDS reads, publishes buffer cur^1
    __syncthreads();
  }

  // epilogue per sub-tile: reduce l, normalize, transpose via Pq, 16B stores
#pragma unroll
  for (int s = 0; s < 4; ++s) {
    float l_i = l_p[s];
    l_i += __shfl_xor(l_i, 16);
    l_i += __shfl_xor(l_i, 32);
    float rl = 1.0f / l_i;
#pragma unroll
    for (int dt = 0; dt < 4; ++dt) {
      bf16x4 ok;
#pragma unroll
      for (int r = 0; r < 4; ++r) ok[r] = (bf16)(o[s][dt][r] * rl);
      *(bf16x4*)(&Pq[wid][l16][dt * 16 + lhi * 4]) = ok;
    }
    bf16x8 r0 = *(const bf16x8*)(&Pq[wid][l16][lhi * 16]);
    bf16x8 r1 = *(const bf16x8*)(&Pq[wid][l16][lhi * 16 + 8]);
    bf16* orow = qbase + (size_t)(q0 + s * 16 + l16) * D3 + lhi * 16;
    *(bf16x8*)(orow) = r0;
    *(bf16x8*)(orow + 8) = r1;
  }
}

// ---------------------------------------------------------------------------
extern "C" void kernel_launch(void* const* d_in, const int* in_sizes, int n_in,
                              void* d_out, int out_size, void* d_ws,
                              size_t ws_size, hipStream_t stream) {
  constexpr int B = 4, S = 2048, D = 1024;

  const float* x = nullptr;
  const float* w_in = nullptr;
  const float* w_out = nullptr;
  const float* b_out = nullptr;
  for (int i = 0; i < n_in; ++i) {
    switch (in_sizes[i]) {
      case 8388608: x = (const float*)d_in[i]; break;
      case 3145728: w_in = (const float*)d_in[i]; break;
      case 1048576: w_out = (const float*)d_in[i]; break;
      case 1024: b_out = (const float*)d_in[i]; break;
    }
  }
  float* out = (float*)d_out;  // [4,2048,1024] fp32

  bf16* qkv = (bf16*)d_ws;
  const size_t need_full = (size_t)B * S * 3 * D * 2;      // 48 MiB (qkv)
  const size_t need_cvt = need_full +
                          ((size_t)B * S * D +              // x  bf16
                           (size_t)3 * D * D +              // w_in bf16
                           (size_t)D * D) * 2;              // w_out bf16

  if (ws_size >= need_cvt) {
    bf16* xb = qkv + (size_t)B * S * 3 * D;
    bf16* w_inb = xb + (size_t)B * S * D;
    bf16* w_outb = w_inb + (size_t)3 * D * D;
    const int nx8 = B * S * D / 8;
    const int nwi8 = 3 * D * D / 8;
    const int nwo8 = D * D / 8;
    cvt_bf16<<<dim3((nx8 + 255) / 256), 256, 0, stream>>>(x, xb, nx8);
    cvt_bf16<<<dim3((nwi8 + 255) / 256), 256, 0, stream>>>(w_in, w_inb, nwi8);
    cvt_bf16<<<dim3((nwo8 + 255) / 256), 256, 0, stream>>>(w_out, w_outb, nwo8);

    gemm_glds<bf16, false><<<dim3(3 * D / 128, B * S / 128), 256, 0, stream>>>(
        xb, w_inb, nullptr, qkv, B * S, 3 * D, D, D);
    attn_fwd<<<dim3(S / 256, B * 16), 256, 0, stream>>>(qkv);
    gemm_glds<float, true><<<dim3(D / 128, B * S / 128), 256, 0, stream>>>(
        qkv, w_outb, b_out, out, B * S, D, D, 3 * D);
  } else if (ws_size >= need_full) {
    gemm_bt<float, bf16, false><<<dim3(3 * D / 128, B * S / 128), 256, 0,
                                  stream>>>(x, w_in, nullptr, qkv, B * S,
                                            3 * D, D, D, 0);
    attn_fwd<<<dim3(S / 256, B * 16), 256, 0, stream>>>(qkv);
    gemm_bt<bf16, float, true><<<dim3(D / 128, B * S / 128), 256, 0, stream>>>(
        qkv, w_out, b_out, out, B * S, D, D, 3 * D, 0);
  } else {
    for (int b0 = 0; b0 < B; ++b0) {
      gemm_bt<float, bf16, false><<<dim3(3 * D / 128, S / 128), 256, 0,
                                    stream>>>(x, w_in, nullptr, qkv, S, 3 * D,
                                              D, D, b0 * S);
      attn_fwd<<<dim3(S / 256, 16), 256, 0, stream>>>(qkv);
      gemm_bt<bf16, float, true><<<dim3(D / 128, S / 128), 256, 0, stream>>>(
          qkv, w_out, b_out, out + (size_t)b0 * S * D, S, D, D, 3 * D, 0);
    }
  }
}

// Round 11
// 315.629 us; speedup vs baseline: 1.0918x; 1.0918x over previous
//
#include <hip/hip_runtime.h>

typedef __bf16 bf16;
typedef __bf16 bf16x2 __attribute__((ext_vector_type(2)));
typedef __bf16 bf16x4 __attribute__((ext_vector_type(4)));
typedef __bf16 bf16x8 __attribute__((ext_vector_type(8)));
typedef float f32x4 __attribute__((ext_vector_type(4)));

typedef __attribute__((address_space(1))) const unsigned int gq_t;
typedef __attribute__((address_space(3))) unsigned int lq_t;

// ---------------------------------------------------------------------------
// fp32 -> bf16 converter, 8 elems/thread.
// ---------------------------------------------------------------------------
__global__ __launch_bounds__(256) void cvt_bf16(const float* __restrict__ in,
                                                bf16* __restrict__ out,
                                                int n8) {
  int i = blockIdx.x * 256 + threadIdx.x;
  if (i >= n8) return;
  f32x4 a = ((const f32x4*)in)[2 * i];
  f32x4 b = ((const f32x4*)in)[2 * i + 1];
  bf16x8 o;
#pragma unroll
  for (int j = 0; j < 4; ++j) {
    o[j] = (bf16)a[j];
    o[4 + j] = (bf16)b[j];
  }
  ((bf16x8*)out)[i] = o;
}

// ---------------------------------------------------------------------------
// bf16 GEMM, glds width-16 staging, 2-PHASE DOUBLE-BUFFERED (T3-minimum,
// m230: 682 TF refcheck'd at this structure). Rounds 8-9 never ran this
// (container died at acquire — no timing dict, vs round-2 kernel-abort which
// produced pytest output). First actual HW test of this kernel.
// Issue next-tile glds BEFORE compute; ONE __syncthreads per K-step (its
// implicit vmcnt(0)+lgkmcnt(0) drain retires loads + ds_reads, publishes the
// buffer). Race-free: glds writes buf^1 while ds_reads hit buf; glds only
// re-targets buf after the barrier at which all buf-reads retired.
// LDS 64 KB -> 2 blocks/CU.
// ---------------------------------------------------------------------------
template <typename TC, bool ADD_BIAS>
__global__ __launch_bounds__(256) void gemm_glds(const bf16* __restrict__ A,
                                                 const bf16* __restrict__ B,
                                                 const float* __restrict__ bias,
                                                 TC* __restrict__ C,
                                                 int M, int N, int K, int lda) {
  __shared__ __align__(16) bf16 As[2][128 * 64];
  __shared__ __align__(16) bf16 Bs[2][128 * 64];
  const int tid = threadIdx.x;
  const int lane = tid & 63;
  const int wid = tid >> 6;
  const int wr = wid >> 1, wc = wid & 1;
  const int m0 = blockIdx.y * 128;
  const int n0 = blockIdx.x * 128;
  const int l16 = lane & 15;
  const int lhi = lane >> 4;
  const int lr = lane >> 3;       // row within 8-row chunk
  const int lc = (lane & 7) * 8;  // col (elems) within row

  f32x4 acc[4][4] = {};

  // prologue: stage K-step 0 into buffer 0
#pragma unroll
  for (int i = 0; i < 4; ++i) {
    const int chunk = wid * 4 + i;
    const int row = chunk * 8 + lr;
    const bf16* ga = A + (size_t)(m0 + row) * lda + lc;
    const bf16* gb = B + (size_t)(n0 + row) * K + lc;
    __builtin_amdgcn_global_load_lds((gq_t*)ga, (lq_t*)&As[0][chunk * 512], 16,
                                     0, 0);
    __builtin_amdgcn_global_load_lds((gq_t*)gb, (lq_t*)&Bs[0][chunk * 512], 16,
                                     0, 0);
  }
  __syncthreads();  // implicit vmcnt(0) drain publishes buffer 0

  int cur = 0;
  for (int k0 = 0; k0 < K; k0 += 64) {
    // issue next K-step's glds FIRST — latency hides under ds_read + MFMA
    if (k0 + 64 < K) {
#pragma unroll
      for (int i = 0; i < 4; ++i) {
        const int chunk = wid * 4 + i;
        const int row = chunk * 8 + lr;
        const bf16* ga = A + (size_t)(m0 + row) * lda + k0 + 64 + lc;
        const bf16* gb = B + (size_t)(n0 + row) * K + k0 + 64 + lc;
        __builtin_amdgcn_global_load_lds((gq_t*)ga,
                                         (lq_t*)&As[cur ^ 1][chunk * 512], 16,
                                         0, 0);
        __builtin_amdgcn_global_load_lds((gq_t*)gb,
                                         (lq_t*)&Bs[cur ^ 1][chunk * 512], 16,
                                         0, 0);
      }
    }
#pragma unroll
    for (int ks = 0; ks < 2; ++ks) {
      bf16x8 af[4], bfr[4];
#pragma unroll
      for (int i = 0; i < 4; ++i) {
        af[i] = *(const bf16x8*)(&As[cur][(wr * 64 + i * 16 + l16) * 64 +
                                          ks * 32 + lhi * 8]);
        bfr[i] = *(const bf16x8*)(&Bs[cur][(wc * 64 + i * 16 + l16) * 64 +
                                           ks * 32 + lhi * 8]);
      }
      __builtin_amdgcn_s_setprio(1);
#pragma unroll
      for (int i = 0; i < 4; ++i)
#pragma unroll
        for (int j = 0; j < 4; ++j)
          acc[i][j] = __builtin_amdgcn_mfma_f32_16x16x32_bf16(af[i], bfr[j],
                                                              acc[i][j], 0, 0, 0);
      __builtin_amdgcn_s_setprio(0);
    }
    // single barrier: drains glds (vmcnt) + ds_reads (lgkm), publishes buf^1
    __syncthreads();
    cur ^= 1;
  }

#pragma unroll
  for (int i = 0; i < 4; ++i) {
    int row_base = m0 + wr * 64 + i * 16 + lhi * 4;
#pragma unroll
    for (int j = 0; j < 4; ++j) {
      int col = n0 + wc * 64 + j * 16 + l16;
      float bv = ADD_BIAS ? bias[col] : 0.0f;
#pragma unroll
      for (int r = 0; r < 4; ++r) {
        float val = acc[i][j][r] + bv;
        if constexpr (__is_same(TC, float))
          C[(size_t)(row_base + r) * N + col] = val;
        else
          C[(size_t)(row_base + r) * N + col] = (bf16)val;
      }
    }
  }
}

// ---------------------------------------------------------------------------
// GEMM (legacy reg-staged, fp32 B): low-workspace fallback only.
// ---------------------------------------------------------------------------
template <typename TA, typename TC, bool ADD_BIAS>
__global__ __launch_bounds__(256) void gemm_bt(const TA* __restrict__ A,
                                               const float* __restrict__ B,
                                               const float* __restrict__ bias,
                                               TC* __restrict__ C,
                                               int M, int N, int K,
                                               int lda, int row0) {
  __shared__ __align__(16) bf16 As[128][72];
  __shared__ __align__(16) bf16 Bs[128][72];
  const int tid = threadIdx.x;
  const int lane = tid & 63;
  const int wid = tid >> 6;
  const int wr = wid >> 1, wc = wid & 1;
  const int m0 = blockIdx.y * 128;
  const int n0 = blockIdx.x * 128;
  const int l16 = lane & 15;
  const int lhi = lane >> 4;

  f32x4 acc[4][4] = {};

  for (int k0 = 0; k0 < K; k0 += 64) {
    __syncthreads();
#pragma unroll
    for (int p = 0; p < 8; ++p) {
      int v = tid + p * 256;
      int row = v >> 4;
      int kc = (v & 15) * 4;
      size_t ai = (size_t)(row0 + m0 + row) * lda + k0 + kc;
      size_t bi = (size_t)(n0 + row) * K + k0 + kc;
      bf16x4 ab, bb;
      if constexpr (__is_same(TA, float)) {
        f32x4 a4 = *(const f32x4*)((const float*)A + ai);
#pragma unroll
        for (int j = 0; j < 4; ++j) ab[j] = (bf16)a4[j];
      } else {
        ab = *(const bf16x4*)((const bf16*)A + ai);
      }
      f32x4 b4 = *(const f32x4*)(B + bi);
#pragma unroll
      for (int j = 0; j < 4; ++j) bb[j] = (bf16)b4[j];
      *(bf16x4*)(&As[row][kc]) = ab;
      *(bf16x4*)(&Bs[row][kc]) = bb;
    }
    __syncthreads();
#pragma unroll
    for (int ks = 0; ks < 2; ++ks) {
      bf16x8 af[4], bfr[4];
#pragma unroll
      for (int i = 0; i < 4; ++i) {
        af[i] = *(const bf16x8*)(&As[wr * 64 + i * 16 + l16][ks * 32 + lhi * 8]);
        bfr[i] = *(const bf16x8*)(&Bs[wc * 64 + i * 16 + l16][ks * 32 + lhi * 8]);
      }
#pragma unroll
      for (int i = 0; i < 4; ++i)
#pragma unroll
        for (int j = 0; j < 4; ++j)
          acc[i][j] = __builtin_amdgcn_mfma_f32_16x16x32_bf16(af[i], bfr[j],
                                                              acc[i][j], 0, 0, 0);
    }
  }

#pragma unroll
  for (int i = 0; i < 4; ++i) {
    int row_base = m0 + wr * 64 + i * 16 + lhi * 4;
#pragma unroll
    for (int j = 0; j < 4; ++j) {
      int col = n0 + wc * 64 + j * 16 + l16;
      float bv = ADD_BIAS ? bias[col] : 0.0f;
#pragma unroll
      for (int r = 0; r < 4; ++r) {
        float val = acc[i][j][r] + bv;
        if constexpr (__is_same(TC, float))
          C[(size_t)(row_base + r) * N + col] = val;
        else
          C[(size_t)(row_base + r) * N + col] = (bf16)val;
      }
    }
  }
}

// ---------------------------------------------------------------------------
// MFMA flash attention v8 (round-7 proven: 143 us; v9's 64-row variant
// REGRESSED to 159 us — occupancy 25->11%, grid 512 = 2 blocks/CU. The
// amortization ladder's optimum is 32 rows/wave; reverted).
// ---------------------------------------------------------------------------
__global__ __launch_bounds__(256) void attn_fwd(bf16* __restrict__ qkv) {
  constexpr int S = 2048, D3 = 3072;
  constexpr float SCL = 0.18033688011112042f;  // 0.125 * log2(e)
  constexpr float THR = 11.5f;                 // 8 * log2(e)
  __shared__ __align__(16) bf16 Kt[2][64][72];  // [buf][key][dim]
  __shared__ __align__(16) bf16 Vt[2][64][72];  // [buf][dim][key]
  __shared__ __align__(16) bf16 Pq[4][16][72];  // per-wave transpose buffer

  const int tid = threadIdx.x;
  const int lane = tid & 63;
  const int wid = tid >> 6;
  const int l16 = lane & 15, lhi = lane >> 4;

  const int nwg = gridDim.x * gridDim.y;
  const int bid = blockIdx.y * gridDim.x + blockIdx.x;
  const int swz = (bid & 7) * (nwg >> 3) + (bid >> 3);
  const int bh = swz >> 4;
  const int b = bh >> 4, h = bh & 15;
  const int q0 = (swz & 15) * 128 + wid * 32;

  bf16* base = qkv + (size_t)b * S * D3;
  bf16* qbase = base + h * 64;
  const bf16* kbase = base + 1024 + h * 64;
  const bf16* vbase = base + 2048 + h * 64;

  bf16x8 qfA[2], qfB[2];
#pragma unroll
  for (int ks = 0; ks < 2; ++ks) {
    qfA[ks] = *(const bf16x8*)(qbase + (size_t)(q0 + l16) * D3 + ks * 32 + lhi * 8);
    qfB[ks] = *(const bf16x8*)(qbase + (size_t)(q0 + 16 + l16) * D3 + ks * 32 + lhi * 8);
  }

  float mA = -1e30f, mB = -1e30f;
  float lA = 0.0f, lB = 0.0f;
  f32x4 oA[4] = {}, oB[4] = {};

  const int kp = tid & 31, oc = tid >> 5;

  {
    bf16x8 k0 = *(const bf16x8*)(kbase + (size_t)(2 * kp) * D3 + oc * 8);
    bf16x8 k1 = *(const bf16x8*)(kbase + (size_t)(2 * kp + 1) * D3 + oc * 8);
    bf16x8 v0 = *(const bf16x8*)(vbase + (size_t)(2 * kp) * D3 + oc * 8);
    bf16x8 v1 = *(const bf16x8*)(vbase + (size_t)(2 * kp + 1) * D3 + oc * 8);
    *(bf16x8*)(&Kt[0][2 * kp][oc * 8]) = k0;
    *(bf16x8*)(&Kt[0][2 * kp + 1][oc * 8]) = k1;
#pragma unroll
    for (int j = 0; j < 8; ++j) {
      bf16x2 pr;
      pr[0] = v0[j];
      pr[1] = v1[j];
      *(bf16x2*)(&Vt[0][oc * 8 + j][2 * kp]) = pr;
    }
  }
  __syncthreads();

  for (int t = 0; t < S; t += 64) {
    const int cur = (t >> 6) & 1;
    const bool havenext = (t + 64 < S);

    bf16x8 kn0, kn1, vn0, vn1;
    if (havenext) {
      const bf16* kb = kbase + (size_t)(t + 64) * D3;
      const bf16* vb = vbase + (size_t)(t + 64) * D3;
      kn0 = *(const bf16x8*)(kb + (size_t)(2 * kp) * D3 + oc * 8);
      kn1 = *(const bf16x8*)(kb + (size_t)(2 * kp + 1) * D3 + oc * 8);
      vn0 = *(const bf16x8*)(vb + (size_t)(2 * kp) * D3 + oc * 8);
      vn1 = *(const bf16x8*)(vb + (size_t)(2 * kp + 1) * D3 + oc * 8);
    }

    f32x4 scA[4] = {}, scB[4] = {};
    __builtin_amdgcn_s_setprio(1);
#pragma unroll
    for (int ct = 0; ct < 4; ++ct) {
#pragma unroll
      for (int ks = 0; ks < 2; ++ks) {
        bf16x8 kf = *(const bf16x8*)(&Kt[cur][ct * 16 + l16][ks * 32 + lhi * 8]);
        scA[ct] = __builtin_amdgcn_mfma_f32_16x16x32_bf16(kf, qfA[ks], scA[ct], 0, 0, 0);
        scB[ct] = __builtin_amdgcn_mfma_f32_16x16x32_bf16(kf, qfB[ks], scB[ct], 0, 0, 0);
      }
    }
    __builtin_amdgcn_s_setprio(0);

    {
      float cm[4];
#pragma unroll
      for (int ct = 0; ct < 4; ++ct)
        cm[ct] = fmaxf(fmaxf(scA[ct][0], scA[ct][1]), fmaxf(scA[ct][2], scA[ct][3]));
      float mxs = fmaxf(fmaxf(cm[0], cm[1]), fmaxf(cm[2], cm[3])) * SCL;
      if (!__all(mxs - mA <= THR)) {
        float mw = mxs;
        mw = fmaxf(mw, __shfl_xor(mw, 16));
        mw = fmaxf(mw, __shfl_xor(mw, 32));
        float nm = fmaxf(mA, mw);
        float alpha = __builtin_amdgcn_exp2f(mA - nm);
        mA = nm;
        lA *= alpha;
#pragma unroll
        for (int dt = 0; dt < 4; ++dt)
#pragma unroll
          for (int r = 0; r < 4; ++r) oA[dt][r] *= alpha;
      }
      float rs4[4];
#pragma unroll
      for (int ct = 0; ct < 4; ++ct) {
#pragma unroll
        for (int r = 0; r < 4; ++r) {
          float p = __builtin_amdgcn_exp2f(__builtin_fmaf(scA[ct][r], SCL, -mA));
          scA[ct][r] = p;
        }
        rs4[ct] = (scA[ct][0] + scA[ct][1]) + (scA[ct][2] + scA[ct][3]);
      }
      lA += (rs4[0] + rs4[1]) + (rs4[2] + rs4[3]);
    }
#pragma unroll
    for (int ct = 0; ct < 4; ++ct) {
      bf16x4 pk;
#pragma unroll
      for (int r = 0; r < 4; ++r) pk[r] = (bf16)scA[ct][r];
      *(bf16x4*)(&Pq[wid][l16][ct * 16 + lhi * 4]) = pk;
    }
    bf16x8 pfA0 = *(const bf16x8*)(&Pq[wid][l16][lhi * 8]);
    bf16x8 pfA1 = *(const bf16x8*)(&Pq[wid][l16][32 + lhi * 8]);

    {
      float cm[4];
#pragma unroll
      for (int ct = 0; ct < 4; ++ct)
        cm[ct] = fmaxf(fmaxf(scB[ct][0], scB[ct][1]), fmaxf(scB[ct][2], scB[ct][3]));
      float mxs = fmaxf(fmaxf(cm[0], cm[1]), fmaxf(cm[2], cm[3])) * SCL;
      if (!__all(mxs - mB <= THR)) {
        float mw = mxs;
        mw = fmaxf(mw, __shfl_xor(mw, 16));
        mw = fmaxf(mw, __shfl_xor(mw, 32));
        float nm = fmaxf(mB, mw);
        float alpha = __builtin_amdgcn_exp2f(mB - nm);
        mB = nm;
        lB *= alpha;
#pragma unroll
        for (int dt = 0; dt < 4; ++dt)
#pragma unroll
          for (int r = 0; r < 4; ++r) oB[dt][r] *= alpha;
      }
      float rs4[4];
#pragma unroll
      for (int ct = 0; ct < 4; ++ct) {
#pragma unroll
        for (int r = 0; r < 4; ++r) {
          float p = __builtin_amdgcn_exp2f(__builtin_fmaf(scB[ct][r], SCL, -mB));
          scB[ct][r] = p;
        }
        rs4[ct] = (scB[ct][0] + scB[ct][1]) + (scB[ct][2] + scB[ct][3]);
      }
      lB += (rs4[0] + rs4[1]) + (rs4[2] + rs4[3]);
    }
#pragma unroll
    for (int ct = 0; ct < 4; ++ct) {
      bf16x4 pk;
#pragma unroll
      for (int r = 0; r < 4; ++r) pk[r] = (bf16)scB[ct][r];
      *(bf16x4*)(&Pq[wid][l16][ct * 16 + lhi * 4]) = pk;
    }
    bf16x8 pfB0 = *(const bf16x8*)(&Pq[wid][l16][lhi * 8]);
    bf16x8 pfB1 = *(const bf16x8*)(&Pq[wid][l16][32 + lhi * 8]);

    if (havenext) {
      *(bf16x8*)(&Kt[cur ^ 1][2 * kp][oc * 8]) = kn0;
      *(bf16x8*)(&Kt[cur ^ 1][2 * kp + 1][oc * 8]) = kn1;
#pragma unroll
      for (int j = 0; j < 8; ++j) {
        bf16x2 pr;
        pr[0] = vn0[j];
        pr[1] = vn1[j];
        *(bf16x2*)(&Vt[cur ^ 1][oc * 8 + j][2 * kp]) = pr;
      }
    }

    __builtin_amdgcn_s_setprio(1);
#pragma unroll
    for (int dt = 0; dt < 4; ++dt) {
      bf16x8 vf0 = *(const bf16x8*)(&Vt[cur][dt * 16 + l16][lhi * 8]);
      bf16x8 vf1 = *(const bf16x8*)(&Vt[cur][dt * 16 + l16][32 + lhi * 8]);
      oA[dt] = __builtin_amdgcn_mfma_f32_16x16x32_bf16(vf0, pfA0, oA[dt], 0, 0, 0);
      oA[dt] = __builtin_amdgcn_mfma_f32_16x16x32_bf16(vf1, pfA1, oA[dt], 0, 0, 0);
      oB[dt] = __builtin_amdgcn_mfma_f32_16x16x32_bf16(vf0, pfB0, oB[dt], 0, 0, 0);
      oB[dt] = __builtin_amdgcn_mfma_f32_16x16x32_bf16(vf1, pfB1, oB[dt], 0, 0, 0);
    }
    __builtin_amdgcn_s_setprio(0);

    __syncthreads();
  }

  {
    float l_i = lA;
    l_i += __shfl_xor(l_i, 16);
    l_i += __shfl_xor(l_i, 32);
    float rl = 1.0f / l_i;
#pragma unroll
    for (int dt = 0; dt < 4; ++dt) {
      bf16x4 ok;
#pragma unroll
      for (int r = 0; r < 4; ++r) ok[r] = (bf16)(oA[dt][r] * rl);
      *(bf16x4*)(&Pq[wid][l16][dt * 16 + lhi * 4]) = ok;
    }
    bf16x8 r0 = *(const bf16x8*)(&Pq[wid][l16][lhi * 16]);
    bf16x8 r1 = *(const bf16x8*)(&Pq[wid][l16][lhi * 16 + 8]);
    bf16* orow = qbase + (size_t)(q0 + l16) * D3 + lhi * 16;
    *(bf16x8*)(orow) = r0;
    *(bf16x8*)(orow + 8) = r1;
  }
  {
    float l_i = lB;
    l_i += __shfl_xor(l_i, 16);
    l_i += __shfl_xor(l_i, 32);
    float rl = 1.0f / l_i;
#pragma unroll
    for (int dt = 0; dt < 4; ++dt) {
      bf16x4 ok;
#pragma unroll
      for (int r = 0; r < 4; ++r) ok[r] = (bf16)(oB[dt][r] * rl);
      *(bf16x4*)(&Pq[wid][l16][dt * 16 + lhi * 4]) = ok;
    }
    bf16x8 r0 = *(const bf16x8*)(&Pq[wid][l16][lhi * 16]);
    bf16x8 r1 = *(const bf16x8*)(&Pq[wid][l16][lhi * 16 + 8]);
    bf16* orow = qbase + (size_t)(q0 + 16 + l16) * D3 + lhi * 16;
    *(bf16x8*)(orow) = r0;
    *(bf16x8*)(orow + 8) = r1;
  }
}

// ---------------------------------------------------------------------------
extern "C" void kernel_launch(void* const* d_in, const int* in_sizes, int n_in,
                              void* d_out, int out_size, void* d_ws,
                              size_t ws_size, hipStream_t stream) {
  constexpr int B = 4, S = 2048, D = 1024;

  const float* x = nullptr;
  const float* w_in = nullptr;
  const float* w_out = nullptr;
  const float* b_out = nullptr;
  for (int i = 0; i < n_in; ++i) {
    switch (in_sizes[i]) {
      case 8388608: x = (const float*)d_in[i]; break;
      case 3145728: w_in = (const float*)d_in[i]; break;
      case 1048576: w_out = (const float*)d_in[i]; break;
      case 1024: b_out = (const float*)d_in[i]; break;
    }
  }
  float* out = (float*)d_out;  // [4,2048,1024] fp32

  bf16* qkv = (bf16*)d_ws;
  const size_t need_full = (size_t)B * S * 3 * D * 2;      // 48 MiB (qkv)
  const size_t need_cvt = need_full +
                          ((size_t)B * S * D +              // x  bf16
                           (size_t)3 * D * D +              // w_in bf16
                           (size_t)D * D) * 2;              // w_out bf16

  if (ws_size >= need_cvt) {
    bf16* xb = qkv + (size_t)B * S * 3 * D;
    bf16* w_inb = xb + (size_t)B * S * D;
    bf16* w_outb = w_inb + (size_t)3 * D * D;
    const int nx8 = B * S * D / 8;
    const int nwi8 = 3 * D * D / 8;
    const int nwo8 = D * D / 8;
    cvt_bf16<<<dim3((nx8 + 255) / 256), 256, 0, stream>>>(x, xb, nx8);
    cvt_bf16<<<dim3((nwi8 + 255) / 256), 256, 0, stream>>>(w_in, w_inb, nwi8);
    cvt_bf16<<<dim3((nwo8 + 255) / 256), 256, 0, stream>>>(w_out, w_outb, nwo8);

    gemm_glds<bf16, false><<<dim3(3 * D / 128, B * S / 128), 256, 0, stream>>>(
        xb, w_inb, nullptr, qkv, B * S, 3 * D, D, D);
    attn_fwd<<<dim3(S / 128, B * 16), 256, 0, stream>>>(qkv);
    gemm_glds<float, true><<<dim3(D / 128, B * S / 128), 256, 0, stream>>>(
        qkv, w_outb, b_out, out, B * S, D, D, 3 * D);
  } else if (ws_size >= need_full) {
    gemm_bt<float, bf16, false><<<dim3(3 * D / 128, B * S / 128), 256, 0,
                                  stream>>>(x, w_in, nullptr, qkv, B * S,
                                            3 * D, D, D, 0);
    attn_fwd<<<dim3(S / 128, B * 16), 256, 0, stream>>>(qkv);
    gemm_bt<bf16, float, true><<<dim3(D / 128, B * S / 128), 256, 0, stream>>>(
        qkv, w_out, b_out, out, B * S, D, D, 3 * D, 0);
  } else {
    for (int b0 = 0; b0 < B; ++b0) {
      gemm_bt<float, bf16, false><<<dim3(3 * D / 128, S / 128), 256, 0,
                                    stream>>>(x, w_in, nullptr, qkv, S, 3 * D,
                                              D, D, b0 * S);
      attn_fwd<<<dim3(S / 128, 16), 256, 0, stream>>>(qkv);
      gemm_bt<bf16, float, true><<<dim3(D / 128, S / 128), 256, 0, stream>>>(
          qkv, w_out, b_out, out + (size_t)b0 * S * D, S, D, D, 3 * D, 0);
    }
  }
}